// Round 1
// baseline (62.872 us; speedup 1.0000x reference)
//
#include <hip/hip_runtime.h>
#include <math.h>

#define EPSF 1e-12f

constexpr int LLEN = 1024;
constexpr int WMAX = 60;
constexpr int LP   = LLEN - WMAX;   // 964
constexpr int NF   = 158;
constexpr int CHUNK = 256;
constexpr int SPAN  = CHUNK + WMAX; // 316
constexpr int NCH   = (LP + CHUNK - 1) / CHUNK; // 4

// Fully-unrolled bitonic sort on a compile-time-size register array.
template<int N>
__device__ __forceinline__ void bitonic_sort(float (&a)[N]) {
#pragma unroll
  for (int k = 2; k <= N; k <<= 1) {
#pragma unroll
    for (int j = k >> 1; j > 0; j >>= 1) {
#pragma unroll
      for (int i = 0; i < N; ++i) {
        int l = i ^ j;
        if (l > i) {
          float x = a[i], y = a[l];
          float mn = fminf(x, y), mx = fmaxf(x, y);
          if ((i & k) == 0) { a[i] = mn; a[l] = mx; }
          else              { a[i] = mx; a[l] = mn; }
        }
      }
    }
  }
}

template<int W, int NP>
__device__ __forceinline__ void process_w(
    const float* cs, const float* hs, const float* ls,
    const float* vs, const float* lgs,
    const float* rr, const float* lc, const float* wvs,
    const float* dcs, const float* dvs,
    int T, float cl, float vol, float* op, int fi)
{
  const int s = T - W + 1;
  const float wf = (float)W;
  const float c0 = cs[s];
  const float lg0 = lgs[s];

  // ---- pass 1: window [s, T] over c,h,l,v,logv ----
  float sc = 0.f, sc2 = 0.f, skc = 0.f;
  float sv = 0.f, sv2 = 0.f;
  float slg = 0.f, slg2 = 0.f, sclg = 0.f;
  int cntle = 0;
  float hmax = -INFINITY, lmin = INFINITY;
  int imax = 0, imin = 0;
  for (int k = 0; k < W; ++k) {
    float cv = cs[s + k];
    float cd = cv - c0;
    sc += cd; sc2 += cd * cd; skc += (float)k * cd;
    cntle += (cv <= cl) ? 1 : 0;
    float hv = hs[s + k];
    if (hv > hmax) { hmax = hv; imax = k; }
    float lv = ls[s + k];
    if (lv < lmin) { lmin = lv; imin = k; }
    float vv = vs[s + k];
    sv += vv; sv2 += vv * vv;
    float ld = lgs[s + k] - lg0;
    slg += ld; slg2 += ld * ld; sclg += cd * ld;
  }

  // ---- pass 2: derived series, j in [T-W, T-1] ----
  float sr = 0.f, sr2 = 0.f, sl = 0.f, sl2 = 0.f, srl = 0.f;
  float sw = 0.f, sw2 = 0.f;
  float sp = 0.f, sn = 0.f, vp = 0.f, vn = 0.f;
  int npos = 0, nneg = 0;
  for (int k = 0; k < W; ++k) {
    int j = T - W + k;
    float r = rr[j];            // ret1 - 1 (shifted; corr is shift-invariant)
    sr += r; sr2 += r * r;
    float lcv = lc[j];
    sl += lcv; sl2 += lcv * lcv; srl += r * lcv;
    float wvv = wvs[j];
    sw += wvv; sw2 += wvv * wvv;
    float d = dcs[j];
    npos += (d > 0.f) ? 1 : 0;
    nneg += (d < 0.f) ? 1 : 0;
    sp += fmaxf(d, 0.f); sn += fmaxf(-d, 0.f);
    float dv = dvs[j];
    vp += fmaxf(dv, 0.f); vn += fmaxf(-dv, 0.f);
  }

  // ---- quantiles via register bitonic sort ----
  float a[NP];
#pragma unroll
  for (int k = 0; k < NP; ++k) a[k] = (k < W) ? cs[s + k] : INFINITY;
  bitonic_sort<NP>(a);
  constexpr double q8d = 0.8 * (W - 1);
  constexpr int    k8  = (int)q8d;
  constexpr float  f8  = (float)(q8d - (double)k8);
  constexpr double q2d = 0.2 * (W - 1);
  constexpr int    k2  = (int)q2d;
  constexpr float  f2  = (float)(q2d - (double)k2);
  float qtlu = a[k8] + f8 * (a[k8 + 1] - a[k8]);
  float qtld = a[k2] + f2 * (a[k2 + 1] - a[k2]);

  // ---- features ----
  constexpr float tm = (W - 1) * 0.5f;
  constexpr float tv = (float)((W * W - 1) / 12.0);

  float roc  = cs[s - 1] / cl;               // close[t-w]/close[t]
  float scm  = sc / wf;
  float ym   = c0 + scm;
  float yvar = fmaxf(sc2 / wf - scm * scm, 0.f);
  float stdv = sqrtf(yvar);
  float cov  = skc / wf - tm * scm;
  float slope = cov / tv;
  float rsqr  = cov * cov / (tv * yvar + EPSF);
  float resi  = (cl - ym) - slope * tm;      // (w-1) - tm == tm

  float cnum = sclg - sc * slg / wf;
  float cden = sqrtf(fmaxf(sc2 - sc * sc / wf, 0.f) *
                     fmaxf(slg2 - slg * slg / wf, 0.f)) + EPSF;
  float corr = cnum / cden;

  float dnum = srl - sr * sl / wf;
  float dden = sqrtf(fmaxf(sr2 - sr * sr / wf, 0.f) *
                     fmaxf(sl2 - sl * sl / wf, 0.f)) + EPSF;
  float cord = dnum / dden;

  float absd = sp + sn;
  float sump = sp / (absd + EPSF);
  float sumn = sn / (absd + EPSF);
  float absv = vp + vn;
  float vsump = vp / (absv + EPSF);
  float vsumn = vn / (absv + EPSF);

  float vAe   = vol + EPSF;
  float vmean = sv / wf;
  float vvar  = fmaxf(sv2 / wf - vmean * vmean, 0.f);
  float wmean = sw / wf;
  float wvar  = fmaxf(sw2 / wf - wmean * wmean, 0.f);

  float cntp = (float)npos / wf;
  float cntn = (float)nneg / wf;

  op[fi + 0]  = roc;
  op[fi + 1]  = ym / cl;
  op[fi + 2]  = stdv / cl;
  op[fi + 3]  = slope / cl;
  op[fi + 4]  = rsqr;
  op[fi + 5]  = resi / cl;
  op[fi + 6]  = hmax / cl;
  op[fi + 7]  = lmin / cl;
  op[fi + 8]  = qtlu / cl;
  op[fi + 9]  = qtld / cl;
  op[fi + 10] = (float)cntle / wf;
  op[fi + 11] = (cl - lmin) / (hmax - lmin + EPSF);
  op[fi + 12] = (float)imax / wf;
  op[fi + 13] = (float)imin / wf;
  op[fi + 14] = (float)(imax - imin) / wf;
  op[fi + 15] = corr;
  op[fi + 16] = cord;
  op[fi + 17] = cntp;
  op[fi + 18] = cntn;
  op[fi + 19] = cntp - cntn;
  op[fi + 20] = sump;
  op[fi + 21] = sumn;
  op[fi + 22] = sump - sumn;
  op[fi + 23] = vmean / vAe;
  op[fi + 24] = sqrtf(vvar) / vAe;
  op[fi + 25] = sqrtf(wvar) / (wmean + EPSF);
  op[fi + 26] = vsump;
  op[fi + 27] = vsumn;
  op[fi + 28] = vsump - vsumn;
}

__global__ __launch_bounds__(256)
void factor_kernel(const float* __restrict__ x, float* __restrict__ out, int B)
{
  __shared__ float cs[SPAN], hs[SPAN], ls[SPAN], vs[SPAN], lgs[SPAN];
  __shared__ float rr[SPAN], lc[SPAN], wvs[SPAN], dcs[SPAN], dvs[SPAN];

  const int b    = blockIdx.x / NCH;
  const int ch   = blockIdx.x % NCH;
  const int t0   = WMAX + ch * CHUNK;              // first global t of chunk
  const int clen = min(CHUNK, LP - ch * CHUNK);
  const int base = t0 - WMAX;                      // global index of local 0
  const int span = clen + WMAX;
  const int tid  = threadIdx.x;

  // stage raw series
  for (int u = tid; u < span; u += 256) {
    const float* p = x + (size_t)(b * LLEN + base + u) * 6;
    float hv = p[1], lv = p[2], cv = p[3], vv = p[4];
    cs[u] = cv; hs[u] = hv; ls[u] = lv; vs[u] = vv;
    lgs[u] = logf(vv + 1.f);
  }
  __syncthreads();

  // derived series (index j refers to pair (j, j+1))
  for (int u = tid; u < span - 1; u += 256) {
    float c0 = cs[u], c1 = cs[u + 1];
    float v0 = vs[u], v1 = vs[u + 1];
    float r = c1 / c0 - 1.f;
    rr[u]  = r;
    dcs[u] = c1 - c0;
    dvs[u] = v1 - v0;
    lc[u]  = logf(v1 / (v0 + EPSF) + 1.f);
    wvs[u] = fabsf(r) * v1;
  }
  __syncthreads();

  if (tid < clen) {
    const int T  = WMAX + tid;     // local index of t
    const int tg = t0 + tid;       // global t
    const float* p = x + (size_t)(b * LLEN + tg) * 6;
    float o = p[0], vwp = p[5];
    float hi = hs[T], lo = ls[T], cl = cs[T], vol = vs[T];

    float* op = out + ((size_t)b * LP + (tg - WMAX)) * NF;

    // base features
    float hl = hi - lo + EPSF;
    float mx_oc = fmaxf(o, cl), mn_oc = fminf(o, cl);
    float body2 = 2.f * cl - hi - lo;
    op[0]  = (cl - o) / o;
    op[1]  = (hi - lo) / o;
    op[2]  = (cl - o) / hl;
    op[3]  = (hi - mx_oc) / o;
    op[4]  = (hi - mx_oc) / hl;
    op[5]  = (mn_oc - lo) / o;
    op[6]  = (mn_oc - lo) / hl;
    op[7]  = body2 / o;
    op[8]  = body2 / hl;
    op[9]  = o / cl;
    op[10] = hi / cl;
    op[11] = lo / cl;
    op[12] = vwp / cl;

    process_w< 5,  8>(cs, hs, ls, vs, lgs, rr, lc, wvs, dcs, dvs, T, cl, vol, op, 13);
    process_w<10, 16>(cs, hs, ls, vs, lgs, rr, lc, wvs, dcs, dvs, T, cl, vol, op, 42);
    process_w<20, 32>(cs, hs, ls, vs, lgs, rr, lc, wvs, dcs, dvs, T, cl, vol, op, 71);
    process_w<30, 32>(cs, hs, ls, vs, lgs, rr, lc, wvs, dcs, dvs, T, cl, vol, op, 100);
    process_w<60, 64>(cs, hs, ls, vs, lgs, rr, lc, wvs, dcs, dvs, T, cl, vol, op, 129);
  }
}

extern "C" void kernel_launch(void* const* d_in, const int* in_sizes, int n_in,
                              void* d_out, int out_size, void* d_ws, size_t ws_size,
                              hipStream_t stream) {
  const float* x = (const float*)d_in[0];
  float* out = (float*)d_out;
  int B = in_sizes[0] / (LLEN * 6);   // 128
  dim3 grid(B * NCH), block(256);
  hipLaunchKernelGGL(factor_kernel, grid, block, 0, stream, x, out, B);
}